// Round 1
// baseline (38.412 us; speedup 1.0000x reference)
//
#include <hip/hip_runtime.h>

#define NB 512   // batches
#define CD 128   // C
#define MD 512   // M (K dimension of the Gram)
#define BK 64    // K-step
#define NT (MD / BK)  // 8

typedef __attribute__((ext_vector_type(8))) short short8;
typedef __attribute__((ext_vector_type(4))) float f32x4;

__device__ __forceinline__ short f2bf(float f) {
  __bf16 h = (__bf16)f;                 // fptrunc -> v_cvt_pk_bf16_f32 (RNE)
  union { __bf16 h; short s; } u; u.h = h;
  return u.s;
}

__global__ __launch_bounds__(256, 2)
void gram_poly_kernel(const float* __restrict__ in, float* __restrict__ out) {
  // 2 x (128 rows x 64 bf16) double-buffered tile = 32 KiB LDS
  __shared__ __align__(16) short lds[2][CD * BK];

  const int n    = blockIdx.x;
  const int tid  = threadIdx.x;
  const int lane = tid & 63;
  const int w    = tid >> 6;        // wave 0..3
  const int wr   = w >> 1;          // wave output-row quadrant
  const int wc   = w & 1;           // wave output-col quadrant

  // staging: 2 threads per row, 32 floats (8 x float4) each
  const int r = tid >> 1;           // row 0..127
  const int h = tid & 1;            // half 0/1
  const float* base = in + (size_t)n * (CD * MD) + (size_t)r * MD + h * 32;
  const int swz_w = (r & 7) * 8;    // XOR swizzle, in shorts (16B granules)

  const int frow = lane & 15;       // fragment row within 16-block
  const int q    = lane >> 4;       // quarter-wave -> k sub-offset

  f32x4 ld[8];
  f32x4 acc[4][4];
  #pragma unroll
  for (int i = 0; i < 4; ++i)
    #pragma unroll
    for (int j = 0; j < 4; ++j) acc[i][j] = (f32x4)0.0f;

  auto LOAD = [&](int t) {
    const f32x4* p = (const f32x4*)(base + t * BK);
    #pragma unroll
    for (int i = 0; i < 8; ++i) ld[i] = p[i];
  };

  auto WRITE = [&](short* buf) {
    short* row = buf + r * BK;
    #pragma unroll
    for (int c = 0; c < 4; ++c) {
      f32x4 a = ld[2 * c], b = ld[2 * c + 1];
      short8 v;
      v[0] = f2bf(a[0]); v[1] = f2bf(a[1]); v[2] = f2bf(a[2]); v[3] = f2bf(a[3]);
      v[4] = f2bf(b[0]); v[5] = f2bf(b[1]); v[6] = f2bf(b[2]); v[7] = f2bf(b[3]);
      *(short8*)(row + ((h * 32 + c * 8) ^ swz_w)) = v;
    }
  };

  auto COMPUTE = [&](const short* buf) {
    short8 afr[4][2], bfr[4][2];
    #pragma unroll
    for (int mi = 0; mi < 4; ++mi) {
      const int rr = wr * 64 + mi * 16 + frow;
      const short* rowp = buf + rr * BK;
      const int sw = (rr & 7) * 8;
      #pragma unroll
      for (int s = 0; s < 2; ++s)
        afr[mi][s] = *(const short8*)(rowp + ((s * 32 + q * 8) ^ sw));
    }
    #pragma unroll
    for (int nj = 0; nj < 4; ++nj) {
      const int rr = wc * 64 + nj * 16 + frow;
      const short* rowp = buf + rr * BK;
      const int sw = (rr & 7) * 8;
      #pragma unroll
      for (int s = 0; s < 2; ++s)
        bfr[nj][s] = *(const short8*)(rowp + ((s * 32 + q * 8) ^ sw));
    }
    #pragma unroll
    for (int s = 0; s < 2; ++s)
      #pragma unroll
      for (int mi = 0; mi < 4; ++mi)
        #pragma unroll
        for (int nj = 0; nj < 4; ++nj)
          acc[mi][nj] = __builtin_amdgcn_mfma_f32_16x16x32_bf16(
              afr[mi][s], bfr[nj][s], acc[mi][nj], 0, 0, 0);
  };

  // prologue
  LOAD(0);
  WRITE(lds[0]);
  __syncthreads();

  for (int t = 0; t < NT; ++t) {
    if (t + 1 < NT) LOAD(t + 1);      // issue next-tile global loads early
    COMPUTE(lds[t & 1]);
    if (t + 1 < NT) {
      WRITE(lds[(t + 1) & 1]);        // vmcnt wait lands here, hidden by MFMA
      __syncthreads();
    }
  }

  // epilogue: (p+1)^2, C/D layout col=lane&15, row=(lane>>4)*4+reg
  float* outp = out + (size_t)n * (CD * CD);
  const int c0 = wc * 64 + (lane & 15);
  const int r0 = wr * 64 + (lane >> 4) * 4;
  #pragma unroll
  for (int mi = 0; mi < 4; ++mi)
    #pragma unroll
    for (int nj = 0; nj < 4; ++nj)
      #pragma unroll
      for (int reg = 0; reg < 4; ++reg) {
        float p = acc[mi][nj][reg] + 1.0f;
        outp[(size_t)(r0 + mi * 16 + reg) * CD + (c0 + nj * 16)] = p * p;
      }
}

extern "C" void kernel_launch(void* const* d_in, const int* in_sizes, int n_in,
                              void* d_out, int out_size, void* d_ws, size_t ws_size,
                              hipStream_t stream) {
  const float* in = (const float*)d_in[0];
  float* out = (float*)d_out;
  gram_poly_kernel<<<NB, 256, 0, stream>>>(in, out);
}

// Round 2
// 29.532 us; speedup vs baseline: 1.3007x; 1.3007x over previous
//
#include <hip/hip_runtime.h>

#define NB 512   // batches
#define CD 128   // C
#define MD 512   // M (K dimension of the Gram)
#define BK 64    // K-step
#define NT (MD / BK)  // 8

typedef __attribute__((ext_vector_type(8))) short short8;
typedef __attribute__((ext_vector_type(4))) float f32x4;

__device__ __forceinline__ short f2bf(float f) {
  __bf16 h = (__bf16)f;                 // fptrunc -> v_cvt_pk_bf16_f32 (RNE)
  union { __bf16 h; short s; } u; u.h = h;
  return u.s;
}

__global__ __launch_bounds__(256, 2)
void gram_poly_kernel(const float* __restrict__ in, float* __restrict__ out) {
  // 2 x (128 rows x 64 bf16) double-buffered tile = 32 KiB LDS
  __shared__ __align__(16) short lds[2][CD * BK];

  const int n    = blockIdx.x;
  const int tid  = threadIdx.x;
  const int lane = tid & 63;
  const int w    = tid >> 6;        // wave 0..3
  const int wr   = w >> 1;          // wave output-row quadrant
  const int wc   = w & 1;           // wave output-col quadrant

  // staging: 2 threads per row, 32 floats (8 x float4) each
  const int r = tid >> 1;           // row 0..127
  const int h = tid & 1;            // half 0/1
  const float* base = in + (size_t)n * (CD * MD) + (size_t)r * MD + h * 32;
  const int swz_w = (r & 7) * 8;    // XOR swizzle, in shorts (16B granules)

  const int frow = lane & 15;       // fragment row within 16-block
  const int q    = lane >> 4;       // quarter-wave -> k sub-offset

  f32x4 ld0[8], ld1[8];             // 2-deep register prefetch (named: no
                                    // runtime indexing -> no scratch)
  f32x4 acc[4][4];
  #pragma unroll
  for (int i = 0; i < 4; ++i)
    #pragma unroll
    for (int j = 0; j < 4; ++j) acc[i][j] = (f32x4)0.0f;

  auto LOAD = [&](int t, f32x4 (&ld)[8]) {
    const f32x4* p = (const f32x4*)(base + t * BK);
    #pragma unroll
    for (int i = 0; i < 8; ++i) ld[i] = p[i];
  };

  auto WRITE = [&](const f32x4 (&ld)[8], short* buf) {
    short* row = buf + r * BK;
    #pragma unroll
    for (int c = 0; c < 4; ++c) {
      f32x4 a = ld[2 * c], b = ld[2 * c + 1];
      short8 v;
      v[0] = f2bf(a[0]); v[1] = f2bf(a[1]); v[2] = f2bf(a[2]); v[3] = f2bf(a[3]);
      v[4] = f2bf(b[0]); v[5] = f2bf(b[1]); v[6] = f2bf(b[2]); v[7] = f2bf(b[3]);
      *(short8*)(row + ((h * 32 + c * 8) ^ swz_w)) = v;
    }
  };

  auto COMPUTE = [&](const short* buf) {
    short8 afr[4][2], bfr[4][2];
    #pragma unroll
    for (int mi = 0; mi < 4; ++mi) {
      const int rr = wr * 64 + mi * 16 + frow;
      const short* rowp = buf + rr * BK;
      const int sw = (rr & 7) * 8;
      #pragma unroll
      for (int s = 0; s < 2; ++s)
        afr[mi][s] = *(const short8*)(rowp + ((s * 32 + q * 8) ^ sw));
    }
    #pragma unroll
    for (int nj = 0; nj < 4; ++nj) {
      const int rr = wc * 64 + nj * 16 + frow;
      const short* rowp = buf + rr * BK;
      const int sw = (rr & 7) * 8;
      #pragma unroll
      for (int s = 0; s < 2; ++s)
        bfr[nj][s] = *(const short8*)(rowp + ((s * 32 + q * 8) ^ sw));
    }
    #pragma unroll
    for (int s = 0; s < 2; ++s)
      #pragma unroll
      for (int mi = 0; mi < 4; ++mi)
        #pragma unroll
        for (int nj = 0; nj < 4; ++nj)
          acc[mi][nj] = __builtin_amdgcn_mfma_f32_16x16x32_bf16(
              afr[mi][s], bfr[nj][s], acc[mi][nj], 0, 0, 0);
  };

  // prologue: 2 tiles in flight before first compute
  LOAD(0, ld0);
  LOAD(1, ld1);
  WRITE(ld0, lds[0]);
  __syncthreads();

  // fully unrolled so all ld-buffer selection is compile-time (rule #20)
  #pragma unroll
  for (int t = 0; t < NT; ++t) {
    // issue tile t+2 into the reg buffer whose tile was just written to LDS
    if (t + 2 < NT) {
      if ((t & 1) == 0) LOAD(t + 2, ld0); else LOAD(t + 2, ld1);
    }
    COMPUTE(lds[t & 1]);
    if (t + 1 < NT) {
      // tile t+1 regs: issued a full K-step ago -> vmcnt wait mostly covered
      if (((t + 1) & 1) == 0) WRITE(ld0, lds[0]); else WRITE(ld1, lds[1]);
      __syncthreads();
    }
  }

  // epilogue: (p+1)^2, C/D layout col=lane&15, row=(lane>>4)*4+reg
  float* outp = out + (size_t)n * (CD * CD);
  const int c0 = wc * 64 + (lane & 15);
  const int r0 = wr * 64 + (lane >> 4) * 4;
  #pragma unroll
  for (int mi = 0; mi < 4; ++mi)
    #pragma unroll
    for (int nj = 0; nj < 4; ++nj)
      #pragma unroll
      for (int reg = 0; reg < 4; ++reg) {
        float p = acc[mi][nj][reg] + 1.0f;
        outp[(size_t)(r0 + mi * 16 + reg) * CD + (c0 + nj * 16)] = p * p;
      }
}

extern "C" void kernel_launch(void* const* d_in, const int* in_sizes, int n_in,
                              void* d_out, int out_size, void* d_ws, size_t ws_size,
                              hipStream_t stream) {
  const float* in = (const float*)d_in[0];
  float* out = (float*)d_out;
  gram_poly_kernel<<<NB, 256, 0, stream>>>(in, out);
}

// Round 3
// 28.652 us; speedup vs baseline: 1.3406x; 1.0307x over previous
//
#include <hip/hip_runtime.h>

#define NB 512   // batches
#define CD 128   // C
#define MD 512   // M (K dimension of the Gram)
#define BK 64    // K-step
#define NT (MD / BK)  // 8

typedef __attribute__((ext_vector_type(8))) short short8;
typedef __attribute__((ext_vector_type(4))) float f32x4;

__device__ __forceinline__ short f2bf(float f) {
  __bf16 h = (__bf16)f;                 // fptrunc -> v_cvt_pk_bf16_f32 (RNE)
  union { __bf16 h; short s; } u; u.h = h;
  return u.s;
}

// 8 waves (512 thr): 16 waves/CU = 4 waves/SIMD at 2 blocks/CU (vs 2/SIMD
// with 256-thr blocks) -> more TLP to cover HBM latency across barriers.
__global__ __launch_bounds__(512, 4)
void gram_poly_kernel(const float* __restrict__ in, float* __restrict__ out) {
  // 2 x (128 rows x 64 bf16) double-buffered tile = 32 KiB LDS
  __shared__ __align__(16) short lds[2][CD * BK];

  const int n    = blockIdx.x;
  const int tid  = threadIdx.x;
  const int lane = tid & 63;
  const int w    = tid >> 6;        // wave 0..7
  const int wr   = w >> 2;          // output-row half (0..1), rows wr*64..+64
  const int wc   = w & 3;           // output-col quarter (0..3), cols wc*32..+32

  // staging: 4 threads per row, 16 floats (4 x float4) each
  const int r = tid >> 2;           // row 0..127
  const int h = tid & 3;            // quarter 0..3
  const float* base = in + (size_t)n * (CD * MD) + (size_t)r * MD + h * 16;
  const int swz_w = (r & 7) * 8;    // XOR swizzle, in shorts (16B granules)

  const int frow = lane & 15;       // fragment row within 16-block
  const int q    = lane >> 4;       // quarter-wave -> k sub-offset

  f32x4 ld0[4], ld1[4];             // 2-deep register prefetch (named: no
                                    // runtime indexing -> no scratch)
  f32x4 acc[4][2];
  #pragma unroll
  for (int i = 0; i < 4; ++i)
    #pragma unroll
    for (int j = 0; j < 2; ++j) acc[i][j] = (f32x4)0.0f;

  auto LOAD = [&](int t, f32x4 (&ld)[4]) {
    const f32x4* p = (const f32x4*)(base + t * BK);
    #pragma unroll
    for (int i = 0; i < 4; ++i) ld[i] = p[i];
  };

  auto WRITE = [&](const f32x4 (&ld)[4], short* buf) {
    short* row = buf + r * BK;
    #pragma unroll
    for (int c = 0; c < 2; ++c) {
      f32x4 a = ld[2 * c], b = ld[2 * c + 1];
      short8 v;
      v[0] = f2bf(a[0]); v[1] = f2bf(a[1]); v[2] = f2bf(a[2]); v[3] = f2bf(a[3]);
      v[4] = f2bf(b[0]); v[5] = f2bf(b[1]); v[6] = f2bf(b[2]); v[7] = f2bf(b[3]);
      *(short8*)(row + ((h * 16 + c * 8) ^ swz_w)) = v;
    }
  };

  auto COMPUTE = [&](const short* buf) {
    short8 afr[4][2], bfr[2][2];
    #pragma unroll
    for (int mi = 0; mi < 4; ++mi) {
      const int rr = wr * 64 + mi * 16 + frow;
      const short* rowp = buf + rr * BK;
      const int sw = (rr & 7) * 8;
      #pragma unroll
      for (int s = 0; s < 2; ++s)
        afr[mi][s] = *(const short8*)(rowp + ((s * 32 + q * 8) ^ sw));
    }
    #pragma unroll
    for (int nj = 0; nj < 2; ++nj) {
      const int rr = wc * 32 + nj * 16 + frow;
      const short* rowp = buf + rr * BK;
      const int sw = (rr & 7) * 8;
      #pragma unroll
      for (int s = 0; s < 2; ++s)
        bfr[nj][s] = *(const short8*)(rowp + ((s * 32 + q * 8) ^ sw));
    }
    #pragma unroll
    for (int s = 0; s < 2; ++s)
      #pragma unroll
      for (int mi = 0; mi < 4; ++mi)
        #pragma unroll
        for (int nj = 0; nj < 2; ++nj)
          acc[mi][nj] = __builtin_amdgcn_mfma_f32_16x16x32_bf16(
              afr[mi][s], bfr[nj][s], acc[mi][nj], 0, 0, 0);
  };

  // prologue: 2 tiles in flight before first compute
  LOAD(0, ld0);
  LOAD(1, ld1);
  WRITE(ld0, lds[0]);
  __syncthreads();

  // fully unrolled so all ld-buffer selection is compile-time (rule #20)
  #pragma unroll
  for (int t = 0; t < NT; ++t) {
    // issue tile t+2 into the reg buffer whose tile was just written to LDS
    if (t + 2 < NT) {
      if ((t & 1) == 0) LOAD(t + 2, ld0); else LOAD(t + 2, ld1);
    }
    COMPUTE(lds[t & 1]);
    if (t + 1 < NT) {
      // tile t+1 regs: issued a full K-step ago -> vmcnt wait mostly covered
      if (((t + 1) & 1) == 0) WRITE(ld0, lds[0]); else WRITE(ld1, lds[1]);
      __syncthreads();
    }
  }

  // epilogue: (p+1)^2, C/D layout col=lane&15, row=(lane>>4)*4+reg
  float* outp = out + (size_t)n * (CD * CD);
  const int c0 = wc * 32 + (lane & 15);
  const int r0 = wr * 64 + (lane >> 4) * 4;
  #pragma unroll
  for (int mi = 0; mi < 4; ++mi)
    #pragma unroll
    for (int nj = 0; nj < 2; ++nj)
      #pragma unroll
      for (int reg = 0; reg < 4; ++reg) {
        float p = acc[mi][nj][reg] + 1.0f;
        outp[(size_t)(r0 + mi * 16 + reg) * CD + (c0 + nj * 16)] = p * p;
      }
}

extern "C" void kernel_launch(void* const* d_in, const int* in_sizes, int n_in,
                              void* d_out, int out_size, void* d_ws, size_t ws_size,
                              hipStream_t stream) {
  const float* in = (const float*)d_in[0];
  float* out = (float*)d_out;
  gram_poly_kernel<<<NB, 512, 0, stream>>>(in, out);
}